// Round 6
// baseline (81.394 us; speedup 1.0000x reference)
//
#include <hip/hip_runtime.h>

#define NPTS 8192
#define NB 2
#define NCH 16                   // y-chunks per batch
#define YCH (NPTS / NCH)         // 512 y-points per chunk
#define NAT 32                   // x-tiles per batch
#define XT (NPTS / NAT)          // 256 x-points per tile
#define SEGY (YCH / 8)           // 64 y-points per segment
#define SEGP 65                  // padded segment stride (float4 / float units)
#define FMAX 3.4028235e38f

// ws layout (floats):
//   row partials [NB][NCH][NPTS] at offset 0        (1 MiB)
//   col partials [NB][NAT][NPTS] at offset ROW_WS   (2 MiB)
#define ROW_WS (NB * NCH * NPTS)

// Phase 1: grid (32 atile, 2 batch, 16 chunk). Each pair computed ONCE.
// Block: 256 x-points x 512 y-points. Thread (g,s)=(t>>3,t&7): 8 x of group g
// vs y-segment s (64 points). d2 = x2 + y2 - 2x.y in 4 ops via merged seeds.
// Row-min (dl): registers + shfl over s-lanes. Col-min (dr): per-j min3 tree
// over 8 x + shfl over g-lanes + per-wave LDS buffer + cross-wave reduce.
__global__ __launch_bounds__(256) void _chamfer_part(const float* __restrict__ x,
                                                     const float* __restrict__ y,
                                                     float* __restrict__ ws) {
    const int atile = blockIdx.x;   // 0..31
    const int batch = blockIdx.y;   // 0..1
    const int c     = blockIdx.z;   // 0..15

    __shared__ float4 ylds[8 * SEGP];        // 8 segs x 64, padded to 65
    __shared__ float  colbuf[4 * 8 * SEGP];  // [wave][s][64], padded to 65

    const int t  = (int)threadIdx.x;
    const int g  = t >> 3;          // x-group 0..31
    const int s  = t & 7;           // y-segment 0..7
    const int wv = t >> 6;          // wave 0..3
    const int gl = g & 7;           // g within wave 0..7

    // Stage y-chunk: threads 0..127 transform 4 points each ->
    // (-2yx, -2yy, -2yz, |y|^2), scattered into padded segments.
    if (t < 128) {
        const float4* ysrc = (const float4*)(y + batch * NPTS * 3 + c * YCH * 3) + t * 3;
        float4 q0 = ysrc[0], q1 = ysrc[1], q2 = ysrc[2];
        float bx[4], by[4], bz[4];
        bx[0]=q0.x; by[0]=q0.y; bz[0]=q0.z;
        bx[1]=q0.w; by[1]=q1.x; bz[1]=q1.y;
        bx[2]=q1.z; by[2]=q1.w; bz[2]=q2.x;
        bx[3]=q2.y; by[3]=q2.z; bz[3]=q2.w;
        #pragma unroll
        for (int i = 0; i < 4; ++i) {
            const int p = t * 4 + i;             // 0..511
            ylds[(p >> 6) * SEGP + (p & 63)] =
                make_float4(-2.f*bx[i], -2.f*by[i], -2.f*bz[i],
                            bx[i]*bx[i] + by[i]*by[i] + bz[i]*bz[i]);
        }
    }

    // Load this group's 8 x-points (8 lanes redundant -> L1 broadcast).
    const int abase = atile * XT + g * 8;
    float ax[8], ay[8], az[8], a2[8], rm[8];
    {
        const float4* asrc = (const float4*)(x + batch * NPTS * 3 + abase * 3);
        float4 q0=asrc[0],q1=asrc[1],q2=asrc[2],q3=asrc[3],q4=asrc[4],q5=asrc[5];
        ax[0]=q0.x; ay[0]=q0.y; az[0]=q0.z;
        ax[1]=q0.w; ay[1]=q1.x; az[1]=q1.y;
        ax[2]=q1.z; ay[2]=q1.w; az[2]=q2.x;
        ax[3]=q2.y; ay[3]=q2.z; az[3]=q2.w;
        ax[4]=q3.x; ay[4]=q3.y; az[4]=q3.z;
        ax[5]=q3.w; ay[5]=q4.x; az[5]=q4.y;
        ax[6]=q4.z; ay[6]=q4.w; az[6]=q5.x;
        ax[7]=q5.y; ay[7]=q5.z; az[7]=q5.w;
    }
    #pragma unroll
    for (int k = 0; k < 8; ++k) {
        a2[k] = ax[k]*ax[k] + ay[k]*ay[k] + az[k]*az[k];
        rm[k] = FMAX;
    }

    __syncthreads();

    const float4* seg  = &ylds[s * SEGP];
    float* colw = &colbuf[wv * 8 * SEGP + s * SEGP];

    #pragma unroll 4
    for (int j = 0; j < SEGY; j += 2) {
        const float4 bA = seg[j];
        const float4 bB = seg[j + 1];
        float dA[8], dB[8];
        #pragma unroll
        for (int k = 0; k < 8; ++k) {
            // d2 = x2 + y2 - 2 x.y : two parallel seeded FMAs + add + final FMA
            dA[k] = fmaf(az[k], bA.z, fmaf(ax[k], bA.x, a2[k]) + fmaf(ay[k], bA.y, bA.w));
            dB[k] = fmaf(az[k], bB.z, fmaf(ax[k], bB.x, a2[k]) + fmaf(ay[k], bB.y, bB.w));
        }
        #pragma unroll
        for (int k = 0; k < 8; ++k)
            rm[k] = fminf(fminf(rm[k], dA[k]), dB[k]);   // v_min3_f32

        // Col candidate: min over this thread's 8 x for each j (min3 trees).
        float ccA = fminf(fminf(fminf(dA[0], dA[1]), dA[2]),
                    fminf(fminf(dA[3], dA[4]), fminf(fminf(dA[5], dA[6]), dA[7])));
        float ccB = fminf(fminf(fminf(dB[0], dB[1]), dB[2]),
                    fminf(fminf(dB[3], dB[4]), fminf(fminf(dB[5], dB[6]), dB[7])));
        // Combine across the wave's 8 g-values (same s, same j): lanes t^8,16,32.
        ccA = fminf(ccA, __shfl_xor(ccA, 8));
        ccB = fminf(ccB, __shfl_xor(ccB, 8));
        ccA = fminf(ccA, __shfl_xor(ccA, 16));
        ccB = fminf(ccB, __shfl_xor(ccB, 16));
        ccA = fminf(ccA, __shfl_xor(ccA, 32));
        ccB = fminf(ccB, __shfl_xor(ccB, 32));
        if (gl == 0) {          // lanes 0..7 of the wave; stride-65 -> no bank conflict
            colw[j]     = ccA;
            colw[j + 1] = ccB;
        }
    }

    // Row finalize: min across the 8 s-lanes of this group, then store 8 floats.
    #pragma unroll
    for (int k = 0; k < 8; ++k) {
        rm[k] = fminf(rm[k], __shfl_xor(rm[k], 1));
        rm[k] = fminf(rm[k], __shfl_xor(rm[k], 2));
        rm[k] = fminf(rm[k], __shfl_xor(rm[k], 4));
    }
    if (s == 0) {
        float4 r0 = make_float4(fmaxf(rm[0],0.f), fmaxf(rm[1],0.f),
                                fmaxf(rm[2],0.f), fmaxf(rm[3],0.f));
        float4 r1 = make_float4(fmaxf(rm[4],0.f), fmaxf(rm[5],0.f),
                                fmaxf(rm[6],0.f), fmaxf(rm[7],0.f));
        float4* w = (float4*)(ws + ((batch * NCH + c) * NPTS + abase));
        w[0] = r0;
        w[1] = r1;
    }

    // Col finalize: min across the 4 waves for each of the 512 j's.
    __syncthreads();
    #pragma unroll
    for (int jj = t; jj < YCH; jj += 256) {
        const int ss = jj >> 6, jl = jj & 63;
        const int o  = ss * SEGP + jl;
        float m = fminf(fminf(colbuf[o], colbuf[8*SEGP + o]),
                        fminf(colbuf[16*SEGP + o], colbuf[24*SEGP + o]));
        ws[ROW_WS + (batch * NAT + atile) * NPTS + c * YCH + jj] = fmaxf(m, 0.f);
    }
}

// Phase 2: dl[b][i] = min over 16 chunk row-partials; dr[b][j] = min over 32
// atile col-partials. Output = dl (2x8192) then dr (2x8192).
__global__ __launch_bounds__(256) void _chamfer_reduce(const float* __restrict__ ws,
                                                       float* __restrict__ out) {
    const int w = blockIdx.x * 256 + (int)threadIdx.x;   // 0..32767
    float m = FMAX;
    if (w < NB * NPTS) {
        const int b = w >> 13, i = w & (NPTS - 1);
        const float* p = ws + b * NCH * NPTS + i;
        #pragma unroll
        for (int c = 0; c < NCH; ++c) m = fminf(m, p[c * NPTS]);
    } else {
        const int v = w - NB * NPTS;
        const int b = v >> 13, j = v & (NPTS - 1);
        const float* p = ws + ROW_WS + b * NAT * NPTS + j;
        #pragma unroll
        for (int a = 0; a < NAT; ++a) m = fminf(m, p[a * NPTS]);
    }
    out[w] = m;
}

extern "C" void kernel_launch(void* const* d_in, const int* in_sizes, int n_in,
                              void* d_out, int out_size, void* d_ws, size_t ws_size,
                              hipStream_t stream) {
    const float* x = (const float*)d_in[0];
    const float* y = (const float*)d_in[1];
    float* ws  = (float*)d_ws;    // uses 3 MiB of the workspace
    float* out = (float*)d_out;

    _chamfer_part<<<dim3(NAT, NB, NCH), dim3(256), 0, stream>>>(x, y, ws);
    _chamfer_reduce<<<dim3(out_size / 256), dim3(256), 0, stream>>>(ws, out);
}

// Round 7
// 73.152 us; speedup vs baseline: 1.1127x; 1.1127x over previous
//
#include <hip/hip_runtime.h>

#define NPTS 8192
#define NB 2
#define MT 128                   // m-points per block (4 waves x 32)
#define NCHK 1024                // n-points per chunk (staged in LDS)
#define NTILE 32                 // 32 n-tiles of 32 points
#define NCHUNKS (NPTS / NCHK)    // 8
#define FMAX 3.4028235e38f

typedef __attribute__((ext_vector_type(8)))  short short8;
typedef __attribute__((ext_vector_type(16))) float f32x16;

__device__ __forceinline__ unsigned short bf16_rne(float f) {
    unsigned u = __float_as_uint(f);
    unsigned r = u + 0x7FFFu + ((u >> 16) & 1u);
    return (unsigned short)(r >> 16);
}
__device__ __forceinline__ float bf16_tof(unsigned short h) {
    return __uint_as_float(((unsigned)h) << 16);
}

// One MFMA emits a full 32x32 d^2 tile via bf16x3-split packing over K=16:
//   k0..2 : xh . yh     (yh = bf16(-2y) hi)
//   k3..5 : xl . yh
//   k6..8 : xh . yl
//   k9,10 : a2h,a2l x 1
//   k11,12: 1 x b2h,b2l
//   k13..15: 0
// => D[m,n] = |x|^2 + |y|^2 - 2 x.y + O(1e-3). Row-mins accumulate in the
// C-layout registers; LDS re-reduce produces per-(row, chunk) partials.
__global__ __launch_bounds__(256) void _chamfer_part(const float* __restrict__ x,
                                                     const float* __restrict__ y,
                                                     float* __restrict__ ws) {
    const int msuper = blockIdx.x;      // 0..63
    const int batch  = blockIdx.y;      // 0..1
    const int dir    = blockIdx.z >> 3; // 0..1
    const int chunk  = blockIdx.z & 7;  // 0..7

    const float* A = dir ? y : x;       // rows  (min taken over B for each A row)
    const float* B = dir ? x : y;

    __shared__ unsigned char lds[NTILE * 1024];  // 32 KB: B-records, then redbuf

    const int t    = (int)threadIdx.x;
    const int lane = t & 63;
    const int wv   = t >> 6;            // wave 0..3 = m-tile within block
    const int col  = lane & 31;
    const int kg   = lane >> 5;         // k-group half

    // ---- stage B fragment-records: 1024 points x 32 B, tile-major ----
    {
        const float4* src = (const float4*)(B + (size_t)batch * NPTS * 3
                                              + (size_t)chunk * NCHK * 3) + t * 3;
        float4 q0 = src[0], q1 = src[1], q2 = src[2];
        float py[4][3] = {{q0.x,q0.y,q0.z},{q0.w,q1.x,q1.y},
                          {q1.z,q1.w,q2.x},{q2.y,q2.z,q2.w}};
        #pragma unroll
        for (int i = 0; i < 4; ++i) {
            const int p  = t * 4 + i;            // 0..1023
            const int tt = p >> 5, cc = p & 31;
            const float vx = py[i][0], vy = py[i][1], vz = py[i][2];
            const float nx = -2.f*vx, ny = -2.f*vy, nz = -2.f*vz;
            const unsigned short h0 = bf16_rne(nx), h1 = bf16_rne(ny), h2 = bf16_rne(nz);
            const unsigned short l0 = bf16_rne(nx - bf16_tof(h0));
            const unsigned short l1 = bf16_rne(ny - bf16_tof(h1));
            const unsigned short l2 = bf16_rne(nz - bf16_tof(h2));
            const float b2 = vx*vx + vy*vy + vz*vz;
            const unsigned short bh = bf16_rne(b2);
            const unsigned short bl = bf16_rne(b2 - bf16_tof(bh));
            uint4 w0, w1;
            w0.x = (unsigned)h0 | ((unsigned)h1 << 16);   // s0=yh0 s1=yh1
            w0.y = (unsigned)h2 | ((unsigned)h0 << 16);   // s2=yh2 s3=yh0
            w0.z = (unsigned)h1 | ((unsigned)h2 << 16);   // s4=yh1 s5=yh2
            w0.w = (unsigned)l0 | ((unsigned)l1 << 16);   // s6=yl0 s7=yl1
            w1.x = (unsigned)l2 | (0x3F80u << 16);        // s8=yl2 s9=1.0
            w1.y = 0x3F80u | ((unsigned)bh << 16);        // s10=1.0 s11=b2h
            w1.z = (unsigned)bl;                          // s12=b2l s13=0
            w1.w = 0u;                                    // s14,s15=0
            uint4* dst = (uint4*)(lds + tt * 1024 + cc * 32);
            dst[0] = w0; dst[1] = w1;
        }
    }

    // ---- build A-fragment in registers (one x-point per lane) ----
    const int mrow = msuper * MT + wv * 32 + col;
    short8 afrag;
    {
        const float* ap = A + (size_t)batch * NPTS * 3 + (size_t)mrow * 3;
        const float vx = ap[0], vy = ap[1], vz = ap[2];
        const unsigned short h0 = bf16_rne(vx), h1 = bf16_rne(vy), h2 = bf16_rne(vz);
        const unsigned short l0 = bf16_rne(vx - bf16_tof(h0));
        const unsigned short l1 = bf16_rne(vy - bf16_tof(h1));
        const unsigned short l2 = bf16_rne(vz - bf16_tof(h2));
        const float a2 = vx*vx + vy*vy + vz*vz;
        const unsigned short ah = bf16_rne(a2);
        const unsigned short al = bf16_rne(a2 - bf16_tof(ah));
        const unsigned short ONE = 0x3F80u;
        if (kg == 0) {
            afrag[0]=(short)h0; afrag[1]=(short)h1; afrag[2]=(short)h2;
            afrag[3]=(short)l0; afrag[4]=(short)l1; afrag[5]=(short)l2;
            afrag[6]=(short)h0; afrag[7]=(short)h1;
        } else {
            afrag[0]=(short)h2; afrag[1]=(short)ah; afrag[2]=(short)al;
            afrag[3]=(short)ONE; afrag[4]=(short)ONE;
            afrag[5]=0; afrag[6]=0; afrag[7]=0;
        }
    }

    f32x16 z, rm;
    #pragma unroll
    for (int q = 0; q < 16; ++q) { z[q] = 0.f; rm[q] = FMAX; }

    __syncthreads();

    // ---- sweep 32 n-tiles: ds_read_b128 (imm offset) + MFMA + min3 ----
    const unsigned char* rbase = lds + col * 32 + kg * 16;
    #pragma unroll
    for (int tt = 0; tt < NTILE; tt += 2) {
        const short8 b0 = *(const short8*)(rbase + tt * 1024);
        const short8 b1 = *(const short8*)(rbase + tt * 1024 + 1024);
        const f32x16 d0 = __builtin_amdgcn_mfma_f32_32x32x16_bf16(afrag, b0, z, 0, 0, 0);
        const f32x16 d1 = __builtin_amdgcn_mfma_f32_32x32x16_bf16(afrag, b1, z, 0, 0, 0);
        #pragma unroll
        for (int q = 0; q < 16; ++q)
            rm[q] = fminf(fminf(rm[q], d0[q]), d1[q]);   // v_min3_f32
    }

    // ---- block row-reduce via LDS (reuse record buffer) ----
    __syncthreads();
    float* red = (float*)lds;            // [4][32][33] floats = 16.5 KB
    #pragma unroll
    for (int q = 0; q < 16; ++q) {
        const int r = (q & 3) + 8 * (q >> 2) + 4 * kg;   // C-layout row
        red[wv * 1056 + r * 33 + col] = rm[q];
    }
    __syncthreads();
    if (t < MT) {
        const float* pr = red + (t >> 5) * 1056 + (t & 31) * 33;
        float m = pr[0];
        #pragma unroll
        for (int c = 1; c < 32; ++c) m = fminf(m, pr[c]);
        ws[(((size_t)dir * NB + batch) * NCHUNKS + chunk) * NPTS + msuper * MT + t]
            = fmaxf(m, 0.f);
    }
}

// Phase 2: min over the 8 chunk partials. Output = dl(2x8192) then dr(2x8192).
__global__ __launch_bounds__(256) void _chamfer_reduce(const float* __restrict__ ws,
                                                       float* __restrict__ out) {
    const int w = blockIdx.x * 256 + (int)threadIdx.x;    // 0..32767
    const int dir = w >> 14, batch = (w >> 13) & 1, i = w & (NPTS - 1);
    const float* p = ws + ((size_t)dir * NB + batch) * NCHUNKS * NPTS + i;
    float m = p[0];
    #pragma unroll
    for (int c = 1; c < NCHUNKS; ++c) m = fminf(m, p[(size_t)c * NPTS]);
    out[w] = m;
}

extern "C" void kernel_launch(void* const* d_in, const int* in_sizes, int n_in,
                              void* d_out, int out_size, void* d_ws, size_t ws_size,
                              hipStream_t stream) {
    const float* x = (const float*)d_in[0];
    const float* y = (const float*)d_in[1];
    float* ws  = (float*)d_ws;    // 2*2*8*8192*4 B = 2 MiB
    float* out = (float*)d_out;

    // 64 m-supers x 2 batches x (2 dirs * 8 chunks) = 2048 blocks
    _chamfer_part<<<dim3(64, NB, 16), dim3(256), 0, stream>>>(x, y, ws);
    _chamfer_reduce<<<dim3(out_size / 256), dim3(256), 0, stream>>>(ws, out);
}

// Round 8
// 72.771 us; speedup vs baseline: 1.1185x; 1.0052x over previous
//
#include <hip/hip_runtime.h>

#define NPTS 8192
#define NB 2
#define MT 128                   // m-points per block (4 waves x 32)
#define TPC 32                   // tiles per chunk (1024 n-points)
#define NCHUNKS 8
#define NTILES 256               // tiles per (dir,batch)
#define FMAX 3.4028235e38f
// ws layout: records [2][NB][NTILES][32B-rec x 32] = 1 MiB, then row partials
#define REC_FLOATS (2 * NB * NPTS * 32 / 4)

typedef __attribute__((ext_vector_type(8)))  short short8;
typedef __attribute__((ext_vector_type(16))) float f32x16;

__device__ __forceinline__ unsigned short bf16_rne(float f) {
    unsigned u = __float_as_uint(f);
    unsigned r = u + 0x7FFFu + ((u >> 16) & 1u);
    return (unsigned short)(r >> 16);
}
__device__ __forceinline__ float bf16_tof(unsigned short h) {
    return __uint_as_float(((unsigned)h) << 16);
}

// Build all B-fragment records ONCE (was rebuilt 64x per chunk with 64-way
// LDS write conflicts inside _chamfer_part). Record = 32 B, K=16 bf16 slots:
//   k0..2=yh(-2y) k3..5=yh k6..8=yl k9,10=1.0 k11=b2h k12=b2l k13..15=0
__global__ __launch_bounds__(256) void _chamfer_prep(const float* __restrict__ x,
                                                     const float* __restrict__ y,
                                                     unsigned char* __restrict__ rec) {
    const int r = blockIdx.x * 256 + (int)threadIdx.x;  // 0..32767
    const int dir = r >> 14, batch = (r >> 13) & 1, p = r & (NPTS - 1);
    const float* src = (dir ? x : y) + ((size_t)batch * NPTS + p) * 3;
    const float vx = src[0], vy = src[1], vz = src[2];
    const float nx = -2.f*vx, ny = -2.f*vy, nz = -2.f*vz;
    const unsigned short h0 = bf16_rne(nx), h1 = bf16_rne(ny), h2 = bf16_rne(nz);
    const unsigned short l0 = bf16_rne(nx - bf16_tof(h0));
    const unsigned short l1 = bf16_rne(ny - bf16_tof(h1));
    const unsigned short l2 = bf16_rne(nz - bf16_tof(h2));
    const float b2 = vx*vx + vy*vy + vz*vz;
    const unsigned short bh = bf16_rne(b2);
    const unsigned short bl = bf16_rne(b2 - bf16_tof(bh));
    uint4 w0, w1;
    w0.x = (unsigned)h0 | ((unsigned)h1 << 16);   // k0=yh0 k1=yh1
    w0.y = (unsigned)h2 | ((unsigned)h0 << 16);   // k2=yh2 k3=yh0
    w0.z = (unsigned)h1 | ((unsigned)h2 << 16);   // k4=yh1 k5=yh2
    w0.w = (unsigned)l0 | ((unsigned)l1 << 16);   // k6=yl0 k7=yl1
    w1.x = (unsigned)l2 | (0x3F80u << 16);        // k8=yl2 k9=1.0
    w1.y = 0x3F80u | ((unsigned)bh << 16);        // k10=1.0 k11=b2h
    w1.z = (unsigned)bl;                          // k12=b2l k13=0
    w1.w = 0u;                                    // k14,k15=0
    uint4* dst = (uint4*)(rec + (((size_t)(dir * NB + batch) * NTILES + (p >> 5)) * 1024
                                 + (size_t)(p & 31) * 32));
    dst[0] = w0; dst[1] = w1;
}

// Grid (64 msuper, 2 batch, 16 = dir*8+chunk). Wave = one 32-row m-tile;
// sweeps 32 pre-packed B-fragments straight from global (L2-resident, each
// fragment read = contiguous 1 KiB/wave). One MFMA per 1024 pairs; row-min
// in C-layout regs; LDS only for the final conflict-free row reduce.
__global__ __launch_bounds__(256) void _chamfer_part(const float* __restrict__ x,
                                                     const float* __restrict__ y,
                                                     const unsigned char* __restrict__ rec,
                                                     float* __restrict__ part) {
    const int msuper = blockIdx.x;      // 0..63
    const int batch  = blockIdx.y;      // 0..1
    const int dir    = blockIdx.z >> 3; // 0..1
    const int chunk  = blockIdx.z & 7;  // 0..7

    const float* A = dir ? y : x;

    __shared__ float red[4 * 32 * 33];  // [wave][row][col+pad] = 16.5 KB

    const int t    = (int)threadIdx.x;
    const int lane = t & 63;
    const int wv   = t >> 6;
    const int col  = lane & 31;
    const int kg   = lane >> 5;

    // ---- A-fragment: one x-point per lane (bf16x3 split + |a|^2 hi/lo) ----
    const int mrow = msuper * MT + wv * 32 + col;
    short8 afrag;
    {
        const float* ap = A + (size_t)batch * NPTS * 3 + (size_t)mrow * 3;
        const float vx = ap[0], vy = ap[1], vz = ap[2];
        const unsigned short h0 = bf16_rne(vx), h1 = bf16_rne(vy), h2 = bf16_rne(vz);
        const unsigned short l0 = bf16_rne(vx - bf16_tof(h0));
        const unsigned short l1 = bf16_rne(vy - bf16_tof(h1));
        const unsigned short l2 = bf16_rne(vz - bf16_tof(h2));
        const float a2 = vx*vx + vy*vy + vz*vz;
        const unsigned short ah = bf16_rne(a2);
        const unsigned short al = bf16_rne(a2 - bf16_tof(ah));
        const unsigned short ONE = 0x3F80u;
        if (kg == 0) {
            afrag[0]=(short)h0; afrag[1]=(short)h1; afrag[2]=(short)h2;
            afrag[3]=(short)l0; afrag[4]=(short)l1; afrag[5]=(short)l2;
            afrag[6]=(short)h0; afrag[7]=(short)h1;
        } else {
            afrag[0]=(short)h2; afrag[1]=(short)ah; afrag[2]=(short)al;
            afrag[3]=(short)ONE; afrag[4]=(short)ONE;
            afrag[5]=0; afrag[6]=0; afrag[7]=0;
        }
    }

    f32x16 z, rm;
    #pragma unroll
    for (int q = 0; q < 16; ++q) { z[q] = 0.f; rm[q] = FMAX; }

    // ---- sweep 32 fragments from global (L2): dwordx4 + MFMA + min3 ----
    const unsigned char* rbase = rec
        + ((size_t)(dir * NB + batch) * NTILES + (size_t)chunk * TPC) * 1024
        + (size_t)col * 32 + (size_t)kg * 16;
    #pragma unroll
    for (int tt = 0; tt < TPC; tt += 2) {
        const short8 b0 = *(const short8*)(rbase + tt * 1024);
        const short8 b1 = *(const short8*)(rbase + tt * 1024 + 1024);
        const f32x16 d0 = __builtin_amdgcn_mfma_f32_32x32x16_bf16(afrag, b0, z, 0, 0, 0);
        const f32x16 d1 = __builtin_amdgcn_mfma_f32_32x32x16_bf16(afrag, b1, z, 0, 0, 0);
        #pragma unroll
        for (int q = 0; q < 16; ++q)
            rm[q] = fminf(fminf(rm[q], d0[q]), d1[q]);   // v_min3_f32
    }

    // ---- block row-reduce (stride-33: conflict-free) ----
    #pragma unroll
    for (int q = 0; q < 16; ++q) {
        const int r = (q & 3) + 8 * (q >> 2) + 4 * kg;   // C-layout row
        red[wv * 1056 + r * 33 + col] = rm[q];
    }
    __syncthreads();
    if (t < MT) {
        const float* pr = red + (t >> 5) * 1056 + (t & 31) * 33;
        float m = pr[0];
        #pragma unroll
        for (int c = 1; c < 32; ++c) m = fminf(m, pr[c]);
        part[(((size_t)dir * NB + batch) * NCHUNKS + chunk) * NPTS + msuper * MT + t]
            = fmaxf(m, 0.f);
    }
}

// Phase 3: min over the 8 chunk partials. Output = dl(2x8192) then dr(2x8192).
__global__ __launch_bounds__(256) void _chamfer_reduce(const float* __restrict__ part,
                                                       float* __restrict__ out) {
    const int w = blockIdx.x * 256 + (int)threadIdx.x;    // 0..32767
    const int dir = w >> 14, batch = (w >> 13) & 1, i = w & (NPTS - 1);
    const float* p = part + ((size_t)dir * NB + batch) * NCHUNKS * NPTS + i;
    float m = p[0];
    #pragma unroll
    for (int c = 1; c < NCHUNKS; ++c) m = fminf(m, p[(size_t)c * NPTS]);
    out[w] = m;
}

extern "C" void kernel_launch(void* const* d_in, const int* in_sizes, int n_in,
                              void* d_out, int out_size, void* d_ws, size_t ws_size,
                              hipStream_t stream) {
    const float* x = (const float*)d_in[0];
    const float* y = (const float*)d_in[1];
    unsigned char* rec = (unsigned char*)d_ws;            // 1 MiB records
    float* part = (float*)d_ws + REC_FLOATS;              // 2 MiB partials
    float* out  = (float*)d_out;

    _chamfer_prep<<<dim3(NB * NB * NPTS / 256), dim3(256), 0, stream>>>(x, y, rec);
    _chamfer_part<<<dim3(64, NB, 16), dim3(256), 0, stream>>>(x, y, rec, part);
    _chamfer_reduce<<<dim3(out_size / 256), dim3(256), 0, stream>>>(part, out);
}